// Round 3
// baseline (481.999 us; speedup 1.0000x reference)
//
#include <hip/hip_runtime.h>
#include <hip/hip_bf16.h>

#define NEG_SLOPE 0.2f
#define BN_EPS 1e-5f

typedef unsigned int uint32;
typedef unsigned short ushort16;

__device__ __forceinline__ ushort16 f2bf(float f) {
    uint32 u = __float_as_uint(f);
    u = (u + 0x7fff + ((u >> 16) & 1)) >> 16;  // round-to-nearest-even
    return (ushort16)u;
}
__device__ __forceinline__ float bfu_lo(uint32 u) { return __uint_as_float(u << 16); }
__device__ __forceinline__ float bfu_hi(uint32 u) { return __uint_as_float(u & 0xffff0000u); }
__device__ __forceinline__ float bf1(ushort16 u) { return __uint_as_float(((uint32)u) << 16); }

// ============================ CSR construction ============================
__global__ void deg_count(const int* __restrict__ ei, int E, int Etot, int* __restrict__ deg) {
    int i = blockIdx.x * blockDim.x + threadIdx.x;
    if (i >= Etot) return;
    int d = (i < E) ? ei[E + i] : i - E;
    atomicAdd(&deg[d], 1);
}

__global__ void scan_block(const int* __restrict__ deg, int* __restrict__ base,
                           int* __restrict__ bsum, int n) {
    __shared__ int s[1024];
    int gid = blockIdx.x * 1024 + threadIdx.x;
    int v = (gid < n) ? deg[gid] : 0;
    s[threadIdx.x] = v;
    __syncthreads();
    for (int off = 1; off < 1024; off <<= 1) {
        int t = (threadIdx.x >= off) ? s[threadIdx.x - off] : 0;
        __syncthreads();
        s[threadIdx.x] += t;
        __syncthreads();
    }
    if (gid < n) base[gid] = s[threadIdx.x] - v;  // exclusive
    if (threadIdx.x == 1023) bsum[blockIdx.x] = s[1023];
}

__global__ void scan_bsum(int* __restrict__ bsum, int nb) {
    if (threadIdx.x == 0 && blockIdx.x == 0) {
        int acc = 0;
        for (int i = 0; i < nb; ++i) { int t = bsum[i]; bsum[i] = acc; acc += t; }
    }
}

__global__ void scan_add(int* __restrict__ base, const int* __restrict__ bsum, int n) {
    int gid = blockIdx.x * 1024 + threadIdx.x;
    if (gid < n) base[gid] += bsum[blockIdx.x];
}

__global__ void csr_scatter(const int* __restrict__ ei, int E, int Etot,
                            const int* __restrict__ base, int* __restrict__ cursor,
                            int* __restrict__ csr_src) {
    int i = blockIdx.x * blockDim.x + threadIdx.x;
    if (i >= Etot) return;
    int s_, d_;
    if (i < E) { s_ = ei[i]; d_ = ei[E + i]; }
    else       { s_ = d_ = i - E; }
    int pos = base[d_] + atomicAdd(&cursor[d_], 1);
    csr_src[pos] = s_;
}

// ==================== tiled GEMM + attention coefficients ====================
// h = x @ W (x:[N,K] f32, W:[K,OC] f32) -> h stored BF16; asrc/adst f32.
template <int K, int OC, int C>
__global__ __launch_bounds__(256) void gemm_att_tiled(
    const float* __restrict__ x, const float* __restrict__ W,
    const float* __restrict__ a_s, const float* __restrict__ a_d,
    ushort16* __restrict__ h, float* __restrict__ asrc, float* __restrict__ adst, int N) {
    constexpr int MT = 128, KB = 32, TM = 8, TN = OC / 16;
    constexpr int XST = KB + 2;
    __shared__ float xs[MT * XST];
    __shared__ float ws[KB * OC];
    __shared__ float sa[MT * 2];
    __shared__ float sd[MT * 2];
    const int tid = threadIdx.x;
    const int ty = tid >> 4, tx = tid & 15;
    const int m0 = blockIdx.x * MT;

    float acc[TM][TN];
#pragma unroll
    for (int i = 0; i < TM; ++i)
#pragma unroll
        for (int j = 0; j < TN; ++j) acc[i][j] = 0.f;

    for (int kc = 0; kc < K; kc += KB) {
        {
            const int colf = (tid & 7) * 4;
            const int rbase = tid >> 3;
#pragma unroll
            for (int p = 0; p < 4; ++p) {
                int row = p * 32 + rbase;
                int gm = m0 + row;
                float4 v = make_float4(0.f, 0.f, 0.f, 0.f);
                if (gm < N) v = *(const float4*)(x + (size_t)gm * K + kc + colf);
                xs[row * XST + colf + 0] = v.x;
                xs[row * XST + colf + 1] = v.y;
                xs[row * XST + colf + 2] = v.z;
                xs[row * XST + colf + 3] = v.w;
            }
        }
        {
            constexpr int tot4 = KB * OC / 4;
            for (int t4 = tid; t4 < tot4; t4 += 256) {
                int fidx = t4 * 4;
                int r = fidx / OC, c = fidx % OC;
                *(float4*)(ws + r * OC + c) = *(const float4*)(W + (size_t)(kc + r) * OC + c);
            }
        }
        __syncthreads();
#pragma unroll
        for (int k = 0; k < KB; ++k) {
            float a[TM], b[TN];
#pragma unroll
            for (int i = 0; i < TM; ++i) a[i] = xs[(ty * TM + i) * XST + k];
#pragma unroll
            for (int j = 0; j < TN; ++j) b[j] = ws[k * OC + tx * TN + j];
#pragma unroll
            for (int i = 0; i < TM; ++i)
#pragma unroll
                for (int j = 0; j < TN; ++j) acc[i][j] += a[i] * b[j];
        }
        __syncthreads();
    }

    sa[tid] = 0.f;
    sd[tid] = 0.f;
    __syncthreads();
    const int head = (tx * TN) / C;
    float asv[TN], adv[TN];
#pragma unroll
    for (int j = 0; j < TN; ++j) { asv[j] = a_s[tx * TN + j]; adv[j] = a_d[tx * TN + j]; }
#pragma unroll
    for (int i = 0; i < TM; ++i) {
        int gm = m0 + ty * TM + i;
        float ps = 0.f, pd = 0.f;
#pragma unroll
        for (int j = 0; j < TN; ++j) { ps += acc[i][j] * asv[j]; pd += acc[i][j] * adv[j]; }
        atomicAdd(&sa[(ty * TM + i) * 2 + head], ps);
        atomicAdd(&sd[(ty * TM + i) * 2 + head], pd);
        if (gm < N) {
            uint32* hrow = (uint32*)(h + (size_t)gm * OC);
#pragma unroll
            for (int j = 0; j < TN; j += 2) {
                uint32 pk = (uint32)f2bf(acc[i][j]) | ((uint32)f2bf(acc[i][j + 1]) << 16);
                hrow[(tx * TN + j) >> 1] = pk;
            }
        }
    }
    __syncthreads();
    {
        int m = tid >> 1, hh = tid & 1;
        int gm = m0 + m;
        if (gm < N) {
            asrc[gm * 2 + hh] = sa[m * 2 + hh];
            adst[gm * 2 + hh] = sd[m * 2 + hh];
        }
    }
}

// ================= layer-1 gather: softmax-agg + bias + BN + ReLU =================
// One wave per dst node; lane t owns channels 2t,2t+1 (same head). 8-deep unroll.
__global__ __launch_bounds__(64) void gat_gather1(
    const int* __restrict__ base, const int* __restrict__ csr_src, int Etot, int N,
    const ushort16* __restrict__ h, const float* __restrict__ asrc,
    const float* __restrict__ adst, const float* __restrict__ b,
    const float* __restrict__ g, const float* __restrict__ be,
    const float* __restrict__ mu, const float* __restrict__ var,
    float* __restrict__ out) {
    const int node = blockIdx.x;
    const int t = threadIdx.x;
    const int hh = t >> 5;
    const int beg = base[node];
    const int end = (node + 1 < N) ? base[node + 1] : Etot;
    const float2 ad = ((const float2*)adst)[node];
    const float advh = hh ? ad.y : ad.x;
    float accx = 0.f, accy = 0.f, ssum = 0.f;
    constexpr int U = 8;
    int e = beg;
    for (; e + U <= end; e += U) {
        int sidx[U];
#pragma unroll
        for (int j = 0; j < U; ++j) sidx[j] = csr_src[e + j];
        uint32 hv[U];
        float2 asv[U];
#pragma unroll
        for (int j = 0; j < U; ++j) {
            asv[j] = ((const float2*)asrc)[sidx[j]];
            hv[j] = *(const uint32*)(h + (size_t)sidx[j] * 128 + 2 * t);
        }
#pragma unroll
        for (int j = 0; j < U; ++j) {
            float ev = (hh ? asv[j].y : asv[j].x) + advh;
            ev = ev > 0.f ? ev : NEG_SLOPE * ev;
            float ex = __expf(ev);
            accx += ex * bfu_lo(hv[j]);
            accy += ex * bfu_hi(hv[j]);
            ssum += ex;
        }
    }
    for (; e < end; ++e) {
        int s_ = csr_src[e];
        float2 as = ((const float2*)asrc)[s_];
        float ev = (hh ? as.y : as.x) + advh;
        ev = ev > 0.f ? ev : NEG_SLOPE * ev;
        float ex = __expf(ev);
        uint32 hv = *(const uint32*)(h + (size_t)s_ * 128 + 2 * t);
        accx += ex * bfu_lo(hv);
        accy += ex * bfu_hi(hv);
        ssum += ex;
    }
    const float inv = 1.f / (ssum + 1e-16f);
    const int c0 = 2 * t, c1 = 2 * t + 1;
    float v0 = accx * inv + b[c0];
    float v1 = accy * inv + b[c1];
    v0 = (v0 - mu[c0]) * rsqrtf(var[c0] + BN_EPS) * g[c0] + be[c0];
    v1 = (v1 - mu[c1]) * rsqrtf(var[c1] + BN_EPS) * g[c1] + be[c1];
    float2 r = make_float2(fmaxf(v0, 0.f), fmaxf(v1, 0.f));
    ((float2*)(out + (size_t)node * 128))[t] = r;
}

// ========= layer-2 gather: softmax-agg + head-mean + bias + BN + pool =========
__global__ __launch_bounds__(64) void gat_gather2(
    const int* __restrict__ base, const int* __restrict__ csr_src, int Etot, int N,
    const ushort16* __restrict__ h2, const float* __restrict__ asrc,
    const float* __restrict__ adst, const int* __restrict__ batch,
    const float* __restrict__ b2, const float* __restrict__ g,
    const float* __restrict__ be, const float* __restrict__ mu,
    const float* __restrict__ var, float* __restrict__ pooled, float* __restrict__ cnt) {
    const int node = blockIdx.x;
    const int t = threadIdx.x;
    const int hh = t >> 5;
    const int beg = base[node];
    const int end = (node + 1 < N) ? base[node + 1] : Etot;
    const float2 ad = ((const float2*)adst)[node];
    const float advh = hh ? ad.y : ad.x;
    float acc = 0.f, ssum = 0.f;
    constexpr int U = 8;
    int e = beg;
    for (; e + U <= end; e += U) {
        int sidx[U];
#pragma unroll
        for (int j = 0; j < U; ++j) sidx[j] = csr_src[e + j];
        ushort16 hv[U];
        float2 asv[U];
#pragma unroll
        for (int j = 0; j < U; ++j) {
            asv[j] = ((const float2*)asrc)[sidx[j]];
            hv[j] = h2[(size_t)sidx[j] * 64 + t];
        }
#pragma unroll
        for (int j = 0; j < U; ++j) {
            float ev = (hh ? asv[j].y : asv[j].x) + advh;
            ev = ev > 0.f ? ev : NEG_SLOPE * ev;
            float ex = __expf(ev);
            acc += ex * bf1(hv[j]);
            ssum += ex;
        }
    }
    for (; e < end; ++e) {
        int s_ = csr_src[e];
        float2 as = ((const float2*)asrc)[s_];
        float ev = (hh ? as.y : as.x) + advh;
        ev = ev > 0.f ? ev : NEG_SLOPE * ev;
        float ex = __expf(ev);
        acc += ex * bf1(h2[(size_t)s_ * 64 + t]);
        ssum += ex;
    }
    float v = acc / (ssum + 1e-16f);
    float other = __shfl_xor(v, 32, 64);
    if (t < 32) {
        float m = 0.5f * (v + other) + b2[t];
        m = (m - mu[t]) * rsqrtf(var[t] + BN_EPS) * g[t] + be[t];
        int gi = batch[node];
        atomicAdd(&pooled[gi * 32 + t], m);
        if (t == 0) atomicAdd(&cnt[gi], 1.f);
    }
}

// ===================== graph mean + log_softmax (32 classes) =====================
__global__ void pool_logsoftmax(const float* __restrict__ pooled, const float* __restrict__ cnt,
                                float* __restrict__ out) {
    const int g = blockIdx.x;
    const int c = threadIdx.x;
    __shared__ float red[32];
    const float v = pooled[g * 32 + c] / fmaxf(cnt[g], 1.0f);
    red[c] = v;
    __syncthreads();
    for (int off = 16; off >= 1; off >>= 1) {
        if (c < off) red[c] = fmaxf(red[c], red[c + off]);
        __syncthreads();
    }
    const float m = red[0];
    __syncthreads();
    red[c] = __expf(v - m);
    __syncthreads();
    for (int off = 16; off >= 1; off >>= 1) {
        if (c < off) red[c] += red[c + off];
        __syncthreads();
    }
    out[g * 32 + c] = v - m - logf(red[0]);
}

extern "C" void kernel_launch(void* const* d_in, const int* in_sizes, int n_in,
                              void* d_out, int out_size, void* d_ws, size_t ws_size,
                              hipStream_t stream) {
    const float* x   = (const float*)d_in[0];
    const int* ei    = (const int*)d_in[1];
    const int* batch = (const int*)d_in[2];
    const float* W1  = (const float*)d_in[3];
    const float* as1 = (const float*)d_in[4];
    const float* ad1 = (const float*)d_in[5];
    const float* b1  = (const float*)d_in[6];
    const float* g1  = (const float*)d_in[7];
    const float* be1 = (const float*)d_in[8];
    const float* mu1 = (const float*)d_in[9];
    const float* vr1 = (const float*)d_in[10];
    const float* W2  = (const float*)d_in[11];
    const float* as2 = (const float*)d_in[12];
    const float* ad2 = (const float*)d_in[13];
    const float* b2  = (const float*)d_in[14];
    const float* g2  = (const float*)d_in[15];
    const float* be2 = (const float*)d_in[16];
    const float* mu2 = (const float*)d_in[17];
    const float* vr2 = (const float*)d_in[18];
    float* out = (float*)d_out;

    const int N = in_sizes[0] / 128;
    const int E = in_sizes[1] / 2;
    const int Etot = E + N;
    const int G = out_size / 32;
    const int NB = (N + 1023) / 1024;

    // ---- workspace layout ----
    float* p = (float*)d_ws;
    size_t o = 0;
    ushort16* h1 = (ushort16*)(p + o); o += (size_t)N * 64;   // N*128 bf16
    ushort16* h2 = (ushort16*)(p + o); o += (size_t)N * 32;   // N*64 bf16
    float* agg1  = p + o; o += (size_t)N * 128;
    float* asrc1 = p + o; o += (size_t)N * 2;
    float* adst1 = p + o; o += (size_t)N * 2;
    float* asrc2 = p + o; o += (size_t)N * 2;
    float* adst2 = p + o; o += (size_t)N * 2;
    int* csr_src = (int*)(p + o); o += (size_t)Etot;
    int* base    = (int*)(p + o); o += (size_t)N;
    int* bsum    = (int*)(p + o); o += 256;
    // zero-initialized region (one memset):
    float* zbase = p + o;
    int* deg     = (int*)(p + o); o += (size_t)N;
    int* cursor  = (int*)(p + o); o += (size_t)N;
    float* pooled = p + o; o += (size_t)G * 32;
    float* cnt    = p + o; o += (size_t)G;
    const size_t zbytes = (size_t)(p + o - zbase) * sizeof(float);
    hipMemsetAsync(zbase, 0, zbytes, stream);

    // ---- CSR build (by destination) ----
    deg_count<<<(Etot + 255) / 256, 256, 0, stream>>>(ei, E, Etot, deg);
    scan_block<<<NB, 1024, 0, stream>>>(deg, base, bsum, N);
    scan_bsum<<<1, 64, 0, stream>>>(bsum, NB);
    scan_add<<<NB, 1024, 0, stream>>>(base, bsum, N);
    csr_scatter<<<(Etot + 255) / 256, 256, 0, stream>>>(ei, E, Etot, base, cursor, csr_src);

    // ---- layer 1 ----
    gemm_att_tiled<128, 128, 64><<<(N + 127) / 128, 256, 0, stream>>>(
        x, W1, as1, ad1, h1, asrc1, adst1, N);
    gat_gather1<<<N, 64, 0, stream>>>(base, csr_src, Etot, N, h1, asrc1, adst1,
                                      b1, g1, be1, mu1, vr1, agg1);
    // ---- layer 2 ----
    gemm_att_tiled<128, 64, 32><<<(N + 127) / 128, 256, 0, stream>>>(
        agg1, W2, as2, ad2, h2, asrc2, adst2, N);
    gat_gather2<<<N, 64, 0, stream>>>(base, csr_src, Etot, N, h2, asrc2, adst2,
                                      batch, b2, g2, be2, mu2, vr2, pooled, cnt);

    // ---- epilogue ----
    pool_logsoftmax<<<G, 32, 0, stream>>>(pooled, cnt, out);
}

// Round 4
// 476.546 us; speedup vs baseline: 1.0114x; 1.0114x over previous
//
#include <hip/hip_runtime.h>
#include <hip/hip_bf16.h>

#define NEG_SLOPE 0.2f
#define BN_EPS 1e-5f

typedef unsigned int uint32;
typedef unsigned short ushort16;

__device__ __forceinline__ ushort16 f2bf(float f) {
    uint32 u = __float_as_uint(f);
    u = (u + 0x7fff + ((u >> 16) & 1)) >> 16;  // round-to-nearest-even
    return (ushort16)u;
}
__device__ __forceinline__ float bfu_lo(uint32 u) { return __uint_as_float(u << 16); }
__device__ __forceinline__ float bfu_hi(uint32 u) { return __uint_as_float(u & 0xffff0000u); }
__device__ __forceinline__ float bf1(ushort16 u) { return __uint_as_float(((uint32)u) << 16); }

// ============================ CSR construction ============================
__global__ void deg_count(const int* __restrict__ ei, int E, int Etot, int* __restrict__ deg) {
    int i = blockIdx.x * blockDim.x + threadIdx.x;
    if (i >= Etot) return;
    int d = (i < E) ? ei[E + i] : i - E;
    atomicAdd(&deg[d], 1);
}

__global__ void scan_block(const int* __restrict__ deg, int* __restrict__ base,
                           int* __restrict__ bsum, int n) {
    __shared__ int s[1024];
    int gid = blockIdx.x * 1024 + threadIdx.x;
    int v = (gid < n) ? deg[gid] : 0;
    s[threadIdx.x] = v;
    __syncthreads();
    for (int off = 1; off < 1024; off <<= 1) {
        int t = (threadIdx.x >= off) ? s[threadIdx.x - off] : 0;
        __syncthreads();
        s[threadIdx.x] += t;
        __syncthreads();
    }
    if (gid < n) base[gid] = s[threadIdx.x] - v;  // exclusive
    if (threadIdx.x == 1023) bsum[blockIdx.x] = s[1023];
}

__global__ void scan_bsum(int* __restrict__ bsum, int nb) {
    if (threadIdx.x == 0 && blockIdx.x == 0) {
        int acc = 0;
        for (int i = 0; i < nb; ++i) { int t = bsum[i]; bsum[i] = acc; acc += t; }
    }
}

__global__ void scan_add(int* __restrict__ base, const int* __restrict__ bsum, int n) {
    int gid = blockIdx.x * 1024 + threadIdx.x;
    if (gid < n) base[gid] += bsum[blockIdx.x];
}

__global__ void csr_scatter(const int* __restrict__ ei, int E, int Etot,
                            const int* __restrict__ base, int* __restrict__ cursor,
                            int* __restrict__ csr_src) {
    int i = blockIdx.x * blockDim.x + threadIdx.x;
    if (i >= Etot) return;
    int s_, d_;
    if (i < E) { s_ = ei[i]; d_ = ei[E + i]; }
    else       { s_ = d_ = i - E; }
    int pos = base[d_] + atomicAdd(&cursor[d_], 1);
    csr_src[pos] = s_;
}

// ==================== tiled GEMM + attention coefficients ====================
// h = x @ W (x:[N,K] f32, W:[K,OC] f32) -> h stored BF16; asrc/adst f32.
template <int K, int OC, int C>
__global__ __launch_bounds__(256) void gemm_att_tiled(
    const float* __restrict__ x, const float* __restrict__ W,
    const float* __restrict__ a_s, const float* __restrict__ a_d,
    ushort16* __restrict__ h, float* __restrict__ asrc, float* __restrict__ adst, int N) {
    constexpr int MT = 128, KB = 32, TM = 8, TN = OC / 16;
    constexpr int XST = KB + 2;
    __shared__ float xs[MT * XST];
    __shared__ float ws[KB * OC];
    __shared__ float sa[MT * 2];
    __shared__ float sd[MT * 2];
    const int tid = threadIdx.x;
    const int ty = tid >> 4, tx = tid & 15;
    const int m0 = blockIdx.x * MT;

    float acc[TM][TN];
#pragma unroll
    for (int i = 0; i < TM; ++i)
#pragma unroll
        for (int j = 0; j < TN; ++j) acc[i][j] = 0.f;

    for (int kc = 0; kc < K; kc += KB) {
        {
            const int colf = (tid & 7) * 4;
            const int rbase = tid >> 3;
#pragma unroll
            for (int p = 0; p < 4; ++p) {
                int row = p * 32 + rbase;
                int gm = m0 + row;
                float4 v = make_float4(0.f, 0.f, 0.f, 0.f);
                if (gm < N) v = *(const float4*)(x + (size_t)gm * K + kc + colf);
                xs[row * XST + colf + 0] = v.x;
                xs[row * XST + colf + 1] = v.y;
                xs[row * XST + colf + 2] = v.z;
                xs[row * XST + colf + 3] = v.w;
            }
        }
        {
            constexpr int tot4 = KB * OC / 4;
            for (int t4 = tid; t4 < tot4; t4 += 256) {
                int fidx = t4 * 4;
                int r = fidx / OC, c = fidx % OC;
                *(float4*)(ws + r * OC + c) = *(const float4*)(W + (size_t)(kc + r) * OC + c);
            }
        }
        __syncthreads();
#pragma unroll
        for (int k = 0; k < KB; ++k) {
            float a[TM], b[TN];
#pragma unroll
            for (int i = 0; i < TM; ++i) a[i] = xs[(ty * TM + i) * XST + k];
#pragma unroll
            for (int j = 0; j < TN; ++j) b[j] = ws[k * OC + tx * TN + j];
#pragma unroll
            for (int i = 0; i < TM; ++i)
#pragma unroll
                for (int j = 0; j < TN; ++j) acc[i][j] += a[i] * b[j];
        }
        __syncthreads();
    }

    sa[tid] = 0.f;
    sd[tid] = 0.f;
    __syncthreads();
    const int head = (tx * TN) / C;
    float asv[TN], adv[TN];
#pragma unroll
    for (int j = 0; j < TN; ++j) { asv[j] = a_s[tx * TN + j]; adv[j] = a_d[tx * TN + j]; }
#pragma unroll
    for (int i = 0; i < TM; ++i) {
        int gm = m0 + ty * TM + i;
        float ps = 0.f, pd = 0.f;
#pragma unroll
        for (int j = 0; j < TN; ++j) { ps += acc[i][j] * asv[j]; pd += acc[i][j] * adv[j]; }
        atomicAdd(&sa[(ty * TM + i) * 2 + head], ps);
        atomicAdd(&sd[(ty * TM + i) * 2 + head], pd);
        if (gm < N) {
            uint32* hrow = (uint32*)(h + (size_t)gm * OC);
#pragma unroll
            for (int j = 0; j < TN; j += 2) {
                uint32 pk = (uint32)f2bf(acc[i][j]) | ((uint32)f2bf(acc[i][j + 1]) << 16);
                hrow[(tx * TN + j) >> 1] = pk;
            }
        }
    }
    __syncthreads();
    {
        int m = tid >> 1, hh = tid & 1;
        int gm = m0 + m;
        if (gm < N) {
            asrc[gm * 2 + hh] = sa[m * 2 + hh];
            adst[gm * 2 + hh] = sd[m * 2 + hh];
        }
    }
}

// ================= layer-1 gather: softmax-agg + bias + BN + ReLU =================
// 4 nodes per 256-thread block; one wave per node (readfirstlane -> scalar CSR path).
// Predicated 8-wide chunks, 2-stage software pipeline.
__global__ __launch_bounds__(256) void gat_gather1(
    const int* __restrict__ base, const int* __restrict__ csr_src, int Etot, int N,
    const ushort16* __restrict__ h, const float* __restrict__ asrc,
    const float* __restrict__ adst, const float* __restrict__ b,
    const float* __restrict__ g, const float* __restrict__ be,
    const float* __restrict__ mu, const float* __restrict__ var,
    float* __restrict__ out) {
    const int node = __builtin_amdgcn_readfirstlane(blockIdx.x * 4 + (threadIdx.x >> 6));
    if (node >= N) return;
    const int t = threadIdx.x & 63;
    const int hh = t >> 5;
    const int beg = base[node];
    const int end = (node + 1 < N) ? base[node + 1] : Etot;
    const int deg = end - beg;
    const int nchunk = (deg + 7) >> 3;
    const float2 ad = ((const float2*)adst)[node];
    const float advh = hh ? ad.y : ad.x;

    float accx = 0.f, accy = 0.f, ssum = 0.f;

    int sA[8], sB[8];
    float mA[8], mB[8];
    uint32 hA[8], hB[8];
    float2 aA[8], aB[8];

    auto loadIdx = [&](int c, int (&s)[8], float (&m)[8]) {
#pragma unroll
        for (int j = 0; j < 8; ++j) {
            int rel = c * 8 + j;
            bool ok = rel < deg;
            s[j] = csr_src[beg + (ok ? rel : 0)];
            m[j] = ok ? 1.f : 0.f;
        }
    };
    auto gath = [&](const int (&s)[8], float2 (&a)[8], uint32 (&hv)[8]) {
#pragma unroll
        for (int j = 0; j < 8; ++j) {
            a[j] = ((const float2*)asrc)[s[j]];
            hv[j] = *(const uint32*)(h + (size_t)s[j] * 128 + 2 * t);
        }
    };
    auto consume = [&](const float2 (&a)[8], const uint32 (&hv)[8], const float (&m)[8]) {
#pragma unroll
        for (int j = 0; j < 8; ++j) {
            float ev = (hh ? a[j].y : a[j].x) + advh;
            ev = ev > 0.f ? ev : NEG_SLOPE * ev;
            float ex = __expf(ev) * m[j];
            accx += ex * bfu_lo(hv[j]);
            accy += ex * bfu_hi(hv[j]);
            ssum += ex;
        }
    };

    loadIdx(0, sA, mA);
    gath(sA, aA, hA);
    int c = 0;
    while (c + 2 <= nchunk) {
        loadIdx(c + 1, sB, mB);
        gath(sB, aB, hB);
        consume(aA, hA, mA);
        if (c + 2 < nchunk) { loadIdx(c + 2, sA, mA); gath(sA, aA, hA); }
        consume(aB, hB, mB);
        c += 2;
    }
    if (c < nchunk) consume(aA, hA, mA);

    const float inv = 1.f / (ssum + 1e-16f);
    const int c0 = 2 * t, c1 = 2 * t + 1;
    float v0 = accx * inv + b[c0];
    float v1 = accy * inv + b[c1];
    v0 = (v0 - mu[c0]) * rsqrtf(var[c0] + BN_EPS) * g[c0] + be[c0];
    v1 = (v1 - mu[c1]) * rsqrtf(var[c1] + BN_EPS) * g[c1] + be[c1];
    float2 r = make_float2(fmaxf(v0, 0.f), fmaxf(v1, 0.f));
    ((float2*)(out + (size_t)node * 128))[t] = r;
}

// ========= layer-2 gather: softmax-agg + head-mean + bias + BN + pool =========
__global__ __launch_bounds__(256) void gat_gather2(
    const int* __restrict__ base, const int* __restrict__ csr_src, int Etot, int N,
    const ushort16* __restrict__ h2, const float* __restrict__ asrc,
    const float* __restrict__ adst, const int* __restrict__ batch,
    const float* __restrict__ b2, const float* __restrict__ g,
    const float* __restrict__ be, const float* __restrict__ mu,
    const float* __restrict__ var, float* __restrict__ pooled, float* __restrict__ cnt) {
    const int node = __builtin_amdgcn_readfirstlane(blockIdx.x * 4 + (threadIdx.x >> 6));
    if (node >= N) return;
    const int t = threadIdx.x & 63;
    const int hh = t >> 5;
    const int beg = base[node];
    const int end = (node + 1 < N) ? base[node + 1] : Etot;
    const int deg = end - beg;
    const int nchunk = (deg + 7) >> 3;
    const float2 ad = ((const float2*)adst)[node];
    const float advh = hh ? ad.y : ad.x;

    float acc = 0.f, ssum = 0.f;

    int sA[8], sB[8];
    float mA[8], mB[8];
    ushort16 hA[8], hB[8];
    float2 aA[8], aB[8];

    auto loadIdx = [&](int c, int (&s)[8], float (&m)[8]) {
#pragma unroll
        for (int j = 0; j < 8; ++j) {
            int rel = c * 8 + j;
            bool ok = rel < deg;
            s[j] = csr_src[beg + (ok ? rel : 0)];
            m[j] = ok ? 1.f : 0.f;
        }
    };
    auto gath = [&](const int (&s)[8], float2 (&a)[8], ushort16 (&hv)[8]) {
#pragma unroll
        for (int j = 0; j < 8; ++j) {
            a[j] = ((const float2*)asrc)[s[j]];
            hv[j] = h2[(size_t)s[j] * 64 + t];
        }
    };
    auto consume = [&](const float2 (&a)[8], const ushort16 (&hv)[8], const float (&m)[8]) {
#pragma unroll
        for (int j = 0; j < 8; ++j) {
            float ev = (hh ? a[j].y : a[j].x) + advh;
            ev = ev > 0.f ? ev : NEG_SLOPE * ev;
            float ex = __expf(ev) * m[j];
            acc += ex * bf1(hv[j]);
            ssum += ex;
        }
    };

    loadIdx(0, sA, mA);
    gath(sA, aA, hA);
    int c = 0;
    while (c + 2 <= nchunk) {
        loadIdx(c + 1, sB, mB);
        gath(sB, aB, hB);
        consume(aA, hA, mA);
        if (c + 2 < nchunk) { loadIdx(c + 2, sA, mA); gath(sA, aA, hA); }
        consume(aB, hB, mB);
        c += 2;
    }
    if (c < nchunk) consume(aA, hA, mA);

    float v = acc / (ssum + 1e-16f);
    float other = __shfl_xor(v, 32, 64);
    if (t < 32) {
        float m = 0.5f * (v + other) + b2[t];
        m = (m - mu[t]) * rsqrtf(var[t] + BN_EPS) * g[t] + be[t];
        int gi = batch[node];
        atomicAdd(&pooled[gi * 32 + t], m);
        if (t == 0) atomicAdd(&cnt[gi], 1.f);
    }
}

// ===================== graph mean + log_softmax (32 classes) =====================
__global__ void pool_logsoftmax(const float* __restrict__ pooled, const float* __restrict__ cnt,
                                float* __restrict__ out) {
    const int g = blockIdx.x;
    const int c = threadIdx.x;
    __shared__ float red[32];
    const float v = pooled[g * 32 + c] / fmaxf(cnt[g], 1.0f);
    red[c] = v;
    __syncthreads();
    for (int off = 16; off >= 1; off >>= 1) {
        if (c < off) red[c] = fmaxf(red[c], red[c + off]);
        __syncthreads();
    }
    const float m = red[0];
    __syncthreads();
    red[c] = __expf(v - m);
    __syncthreads();
    for (int off = 16; off >= 1; off >>= 1) {
        if (c < off) red[c] += red[c + off];
        __syncthreads();
    }
    out[g * 32 + c] = v - m - logf(red[0]);
}

extern "C" void kernel_launch(void* const* d_in, const int* in_sizes, int n_in,
                              void* d_out, int out_size, void* d_ws, size_t ws_size,
                              hipStream_t stream) {
    const float* x   = (const float*)d_in[0];
    const int* ei    = (const int*)d_in[1];
    const int* batch = (const int*)d_in[2];
    const float* W1  = (const float*)d_in[3];
    const float* as1 = (const float*)d_in[4];
    const float* ad1 = (const float*)d_in[5];
    const float* b1  = (const float*)d_in[6];
    const float* g1  = (const float*)d_in[7];
    const float* be1 = (const float*)d_in[8];
    const float* mu1 = (const float*)d_in[9];
    const float* vr1 = (const float*)d_in[10];
    const float* W2  = (const float*)d_in[11];
    const float* as2 = (const float*)d_in[12];
    const float* ad2 = (const float*)d_in[13];
    const float* b2  = (const float*)d_in[14];
    const float* g2  = (const float*)d_in[15];
    const float* be2 = (const float*)d_in[16];
    const float* mu2 = (const float*)d_in[17];
    const float* vr2 = (const float*)d_in[18];
    float* out = (float*)d_out;

    const int N = in_sizes[0] / 128;
    const int E = in_sizes[1] / 2;
    const int Etot = E + N;
    const int G = out_size / 32;
    const int NB = (N + 1023) / 1024;

    // ---- workspace layout ----
    float* p = (float*)d_ws;
    size_t o = 0;
    ushort16* h1 = (ushort16*)(p + o); o += (size_t)N * 64;   // N*128 bf16
    ushort16* h2 = (ushort16*)(p + o); o += (size_t)N * 32;   // N*64 bf16
    float* agg1  = p + o; o += (size_t)N * 128;
    float* asrc1 = p + o; o += (size_t)N * 2;
    float* adst1 = p + o; o += (size_t)N * 2;
    float* asrc2 = p + o; o += (size_t)N * 2;
    float* adst2 = p + o; o += (size_t)N * 2;
    int* csr_src = (int*)(p + o); o += (size_t)Etot;
    int* base    = (int*)(p + o); o += (size_t)N;
    int* bsum    = (int*)(p + o); o += 256;
    // zero-initialized region (one memset):
    float* zbase = p + o;
    int* deg     = (int*)(p + o); o += (size_t)N;
    int* cursor  = (int*)(p + o); o += (size_t)N;
    float* pooled = p + o; o += (size_t)G * 32;
    float* cnt    = p + o; o += (size_t)G;
    const size_t zbytes = (size_t)(p + o - zbase) * sizeof(float);
    hipMemsetAsync(zbase, 0, zbytes, stream);

    // ---- CSR build (by destination) ----
    deg_count<<<(Etot + 255) / 256, 256, 0, stream>>>(ei, E, Etot, deg);
    scan_block<<<NB, 1024, 0, stream>>>(deg, base, bsum, N);
    scan_bsum<<<1, 64, 0, stream>>>(bsum, NB);
    scan_add<<<NB, 1024, 0, stream>>>(base, bsum, N);
    csr_scatter<<<(Etot + 255) / 256, 256, 0, stream>>>(ei, E, Etot, base, cursor, csr_src);

    // ---- layer 1 ----
    gemm_att_tiled<128, 128, 64><<<(N + 127) / 128, 256, 0, stream>>>(
        x, W1, as1, ad1, h1, asrc1, adst1, N);
    gat_gather1<<<(N + 3) / 4, 256, 0, stream>>>(base, csr_src, Etot, N, h1, asrc1, adst1,
                                                 b1, g1, be1, mu1, vr1, agg1);
    // ---- layer 2 ----
    gemm_att_tiled<128, 64, 32><<<(N + 127) / 128, 256, 0, stream>>>(
        agg1, W2, as2, ad2, h2, asrc2, adst2, N);
    gat_gather2<<<(N + 3) / 4, 256, 0, stream>>>(base, csr_src, Etot, N, h2, asrc2, adst2,
                                                 batch, b2, g2, be2, mu2, vr2, pooled, cnt);

    // ---- epilogue ----
    pool_logsoftmax<<<G, 32, 0, stream>>>(pooled, cnt, out);
}

// Round 5
// 392.519 us; speedup vs baseline: 1.2280x; 1.2141x over previous
//
#include <hip/hip_runtime.h>
#include <hip/hip_bf16.h>

#define NEG_SLOPE 0.2f
#define BN_EPS 1e-5f

typedef unsigned int uint32;
typedef unsigned short ushort16;

__device__ __forceinline__ ushort16 f2bf(float f) {
    uint32 u = __float_as_uint(f);
    u = (u + 0x7fff + ((u >> 16) & 1)) >> 16;  // round-to-nearest-even
    return (ushort16)u;
}
__device__ __forceinline__ float bfu_lo(uint32 u) { return __uint_as_float(u << 16); }
__device__ __forceinline__ float bfu_hi(uint32 u) { return __uint_as_float(u & 0xffff0000u); }

// ============================ CSR construction ============================
__global__ void deg_count(const int* __restrict__ ei, int E, int Etot, int* __restrict__ deg) {
    int i = blockIdx.x * blockDim.x + threadIdx.x;
    if (i >= Etot) return;
    int d = (i < E) ? ei[E + i] : i - E;
    atomicAdd(&deg[d], 1);
}

__global__ void scan_block(const int* __restrict__ deg, int* __restrict__ base,
                           int* __restrict__ bsum, int n) {
    __shared__ int s[1024];
    int gid = blockIdx.x * 1024 + threadIdx.x;
    int v = (gid < n) ? deg[gid] : 0;
    s[threadIdx.x] = v;
    __syncthreads();
    for (int off = 1; off < 1024; off <<= 1) {
        int t = (threadIdx.x >= off) ? s[threadIdx.x - off] : 0;
        __syncthreads();
        s[threadIdx.x] += t;
        __syncthreads();
    }
    if (gid < n) base[gid] = s[threadIdx.x] - v;  // exclusive
    if (threadIdx.x == 1023) bsum[blockIdx.x] = s[1023];
}

__global__ void scan_bsum(int* __restrict__ bsum, int nb) {
    if (threadIdx.x == 0 && blockIdx.x == 0) {
        int acc = 0;
        for (int i = 0; i < nb; ++i) { int t = bsum[i]; bsum[i] = acc; acc += t; }
    }
}

__global__ void scan_add(int* __restrict__ base, const int* __restrict__ bsum, int n) {
    int gid = blockIdx.x * 1024 + threadIdx.x;
    if (gid < n) base[gid] += bsum[blockIdx.x];
}

__global__ void csr_scatter(const int* __restrict__ ei, int E, int Etot,
                            const int* __restrict__ base, int* __restrict__ cursor,
                            int* __restrict__ csr_src) {
    int i = blockIdx.x * blockDim.x + threadIdx.x;
    if (i >= Etot) return;
    int s_, d_;
    if (i < E) { s_ = ei[i]; d_ = ei[E + i]; }
    else       { s_ = d_ = i - E; }
    int pos = base[d_] + atomicAdd(&cursor[d_], 1);
    csr_src[pos] = s_;
}

// gstart[g] = first node with batch[node] >= g (batch sorted); gstart[G] = N.
__global__ void graph_bounds(const int* __restrict__ batch, int N, int G,
                             int* __restrict__ gstart) {
    int g = blockIdx.x * blockDim.x + threadIdx.x;
    if (g > G) return;
    if (g == G) { gstart[G] = N; return; }
    int lo = 0, hi = N;
    while (lo < hi) { int mid = (lo + hi) >> 1; if (batch[mid] < g) lo = mid + 1; else hi = mid; }
    gstart[g] = lo;
}

// ==================== tiled GEMM + attention coefficients ====================
// h = x @ W (x:[N,K] f32, W:[K,OC] f32) -> h stored BF16; asrc/adst f32.
template <int K, int OC, int C>
__global__ __launch_bounds__(256) void gemm_att_tiled(
    const float* __restrict__ x, const float* __restrict__ W,
    const float* __restrict__ a_s, const float* __restrict__ a_d,
    ushort16* __restrict__ h, float* __restrict__ asrc, float* __restrict__ adst, int N) {
    constexpr int MT = 128, KB = 32, TM = 8, TN = OC / 16;
    constexpr int XST = KB + 2;
    __shared__ float xs[MT * XST];
    __shared__ float ws[KB * OC];
    __shared__ float sa[MT * 2];
    __shared__ float sd[MT * 2];
    const int tid = threadIdx.x;
    const int ty = tid >> 4, tx = tid & 15;
    const int m0 = blockIdx.x * MT;

    float acc[TM][TN];
#pragma unroll
    for (int i = 0; i < TM; ++i)
#pragma unroll
        for (int j = 0; j < TN; ++j) acc[i][j] = 0.f;

    for (int kc = 0; kc < K; kc += KB) {
        {
            const int colf = (tid & 7) * 4;
            const int rbase = tid >> 3;
#pragma unroll
            for (int p = 0; p < 4; ++p) {
                int row = p * 32 + rbase;
                int gm = m0 + row;
                float4 v = make_float4(0.f, 0.f, 0.f, 0.f);
                if (gm < N) v = *(const float4*)(x + (size_t)gm * K + kc + colf);
                xs[row * XST + colf + 0] = v.x;
                xs[row * XST + colf + 1] = v.y;
                xs[row * XST + colf + 2] = v.z;
                xs[row * XST + colf + 3] = v.w;
            }
        }
        {
            constexpr int tot4 = KB * OC / 4;
            for (int t4 = tid; t4 < tot4; t4 += 256) {
                int fidx = t4 * 4;
                int r = fidx / OC, c = fidx % OC;
                *(float4*)(ws + r * OC + c) = *(const float4*)(W + (size_t)(kc + r) * OC + c);
            }
        }
        __syncthreads();
#pragma unroll
        for (int k = 0; k < KB; ++k) {
            float a[TM], b[TN];
#pragma unroll
            for (int i = 0; i < TM; ++i) a[i] = xs[(ty * TM + i) * XST + k];
#pragma unroll
            for (int j = 0; j < TN; ++j) b[j] = ws[k * OC + tx * TN + j];
#pragma unroll
            for (int i = 0; i < TM; ++i)
#pragma unroll
                for (int j = 0; j < TN; ++j) acc[i][j] += a[i] * b[j];
        }
        __syncthreads();
    }

    sa[tid] = 0.f;
    sd[tid] = 0.f;
    __syncthreads();
    const int head = (tx * TN) / C;
    float asv[TN], adv[TN];
#pragma unroll
    for (int j = 0; j < TN; ++j) { asv[j] = a_s[tx * TN + j]; adv[j] = a_d[tx * TN + j]; }
#pragma unroll
    for (int i = 0; i < TM; ++i) {
        int gm = m0 + ty * TM + i;
        float ps = 0.f, pd = 0.f;
#pragma unroll
        for (int j = 0; j < TN; ++j) { ps += acc[i][j] * asv[j]; pd += acc[i][j] * adv[j]; }
        atomicAdd(&sa[(ty * TM + i) * 2 + head], ps);
        atomicAdd(&sd[(ty * TM + i) * 2 + head], pd);
        if (gm < N) {
            uint32* hrow = (uint32*)(h + (size_t)gm * OC);
#pragma unroll
            for (int j = 0; j < TN; j += 2) {
                uint32 pk = (uint32)f2bf(acc[i][j]) | ((uint32)f2bf(acc[i][j + 1]) << 16);
                hrow[(tx * TN + j) >> 1] = pk;
            }
        }
    }
    __syncthreads();
    {
        int m = tid >> 1, hh = tid & 1;
        int gm = m0 + m;
        if (gm < N) {
            asrc[gm * 2 + hh] = sa[m * 2 + hh];
            adst[gm * 2 + hh] = sd[m * 2 + hh];
        }
    }
}

// ================= layer-1 gather: softmax-agg + bias + BN + ReLU =================
// 4 nodes / 256-thread block, one wave per node. Two edges in flight per wave:
// lanes 0-31 even edge slots, lanes 32-63 odd slots; lane owns 4 channels (uint2 bf16).
__global__ __launch_bounds__(256) void gat_gather1(
    const int* __restrict__ base, const int* __restrict__ csr_src, int Etot, int N,
    const ushort16* __restrict__ h, const float* __restrict__ asrc,
    const float* __restrict__ adst, const float* __restrict__ b,
    const float* __restrict__ g, const float* __restrict__ be,
    const float* __restrict__ mu, const float* __restrict__ var,
    float* __restrict__ out) {
    const int node = __builtin_amdgcn_readfirstlane(blockIdx.x * 4 + (threadIdx.x >> 6));
    if (node >= N) return;
    const int t = threadIdx.x & 63;
    const int half = t >> 5;
    const int q = t & 31;      // channels 4q..4q+3
    const int hh = q >> 4;     // head
    const int beg = base[node];
    const int end = (node + 1 < N) ? base[node + 1] : Etot;
    const int deg = end - beg;
    const int nk = (deg - half + 1) >> 1;   // valid slots for this lane
    const int nkmax = (deg + 1) >> 1;
    const float2 ad = ((const float2*)adst)[node];
    const float advh = hh ? ad.y : ad.x;

    float a0 = 0.f, a1 = 0.f, a2 = 0.f, a3 = 0.f, ssum = 0.f;
    constexpr int U = 4;
    for (int k = 0; k < nkmax; k += U) {
        int sidx[U];
        float msk[U];
#pragma unroll
        for (int j = 0; j < U; ++j) {
            int kk = k + j;
            bool ok = kk < nk;
            sidx[j] = csr_src[beg + (ok ? 2 * kk + half : 0)];
            msk[j] = ok ? 1.f : 0.f;
        }
        float2 av[U];
        uint2 hv[U];
#pragma unroll
        for (int j = 0; j < U; ++j) {
            av[j] = ((const float2*)asrc)[sidx[j]];
            hv[j] = *(const uint2*)((const ushort16*)h + (size_t)sidx[j] * 128 + 4 * q);
        }
#pragma unroll
        for (int j = 0; j < U; ++j) {
            float ev = (hh ? av[j].y : av[j].x) + advh;
            ev = ev > 0.f ? ev : NEG_SLOPE * ev;
            float ex = __expf(ev) * msk[j];
            a0 += ex * bfu_lo(hv[j].x);
            a1 += ex * bfu_hi(hv[j].x);
            a2 += ex * bfu_lo(hv[j].y);
            a3 += ex * bfu_hi(hv[j].y);
            ssum += ex;
        }
    }
    // merge the two half-wave edge subsets (same channels, same head)
    a0 += __shfl_xor(a0, 32, 64);
    a1 += __shfl_xor(a1, 32, 64);
    a2 += __shfl_xor(a2, 32, 64);
    a3 += __shfl_xor(a3, 32, 64);
    ssum += __shfl_xor(ssum, 32, 64);
    if (half == 0) {
        const float inv = 1.f / (ssum + 1e-16f);
        const int c0 = 4 * q;
        float4 bb = *(const float4*)(b + c0);
        float4 gg = *(const float4*)(g + c0);
        float4 ee = *(const float4*)(be + c0);
        float4 mm = *(const float4*)(mu + c0);
        float4 vv = *(const float4*)(var + c0);
        float v0 = a0 * inv + bb.x, v1 = a1 * inv + bb.y;
        float v2 = a2 * inv + bb.z, v3 = a3 * inv + bb.w;
        v0 = (v0 - mm.x) * rsqrtf(vv.x + BN_EPS) * gg.x + ee.x;
        v1 = (v1 - mm.y) * rsqrtf(vv.y + BN_EPS) * gg.y + ee.y;
        v2 = (v2 - mm.z) * rsqrtf(vv.z + BN_EPS) * gg.z + ee.z;
        v3 = (v3 - mm.w) * rsqrtf(vv.w + BN_EPS) * gg.w + ee.w;
        float4 r = make_float4(fmaxf(v0, 0.f), fmaxf(v1, 0.f), fmaxf(v2, 0.f), fmaxf(v3, 0.f));
        *(float4*)(out + (size_t)node * 128 + c0) = r;
    }
}

// ====== layer-2 gather: softmax-agg + head-mean + bias + BN -> node_out (no atomics) ======
__global__ __launch_bounds__(256) void gat_gather2(
    const int* __restrict__ base, const int* __restrict__ csr_src, int Etot, int N,
    const ushort16* __restrict__ h2, const float* __restrict__ asrc,
    const float* __restrict__ adst, const float* __restrict__ b2,
    const float* __restrict__ g, const float* __restrict__ be,
    const float* __restrict__ mu, const float* __restrict__ var,
    float* __restrict__ node_out) {
    const int node = __builtin_amdgcn_readfirstlane(blockIdx.x * 4 + (threadIdx.x >> 6));
    if (node >= N) return;
    const int t = threadIdx.x & 63;
    const int half = t >> 5;
    const int q = t & 31;      // channels 2q, 2q+1
    const int hh = q >> 4;     // head
    const int beg = base[node];
    const int end = (node + 1 < N) ? base[node + 1] : Etot;
    const int deg = end - beg;
    const int nk = (deg - half + 1) >> 1;
    const int nkmax = (deg + 1) >> 1;
    const float2 ad = ((const float2*)adst)[node];
    const float advh = hh ? ad.y : ad.x;

    float accx = 0.f, accy = 0.f, ssum = 0.f;
    constexpr int U = 4;
    for (int k = 0; k < nkmax; k += U) {
        int sidx[U];
        float msk[U];
#pragma unroll
        for (int j = 0; j < U; ++j) {
            int kk = k + j;
            bool ok = kk < nk;
            sidx[j] = csr_src[beg + (ok ? 2 * kk + half : 0)];
            msk[j] = ok ? 1.f : 0.f;
        }
        float2 av[U];
        uint32 hv[U];
#pragma unroll
        for (int j = 0; j < U; ++j) {
            av[j] = ((const float2*)asrc)[sidx[j]];
            hv[j] = *(const uint32*)((const ushort16*)h2 + (size_t)sidx[j] * 64 + 2 * q);
        }
#pragma unroll
        for (int j = 0; j < U; ++j) {
            float ev = (hh ? av[j].y : av[j].x) + advh;
            ev = ev > 0.f ? ev : NEG_SLOPE * ev;
            float ex = __expf(ev) * msk[j];
            accx += ex * bfu_lo(hv[j]);
            accy += ex * bfu_hi(hv[j]);
            ssum += ex;
        }
    }
    accx += __shfl_xor(accx, 32, 64);
    accy += __shfl_xor(accy, 32, 64);
    ssum += __shfl_xor(ssum, 32, 64);
    const float inv = 1.f / (ssum + 1e-16f);
    float v0 = accx * inv;   // channel 2q
    float v1 = accy * inv;   // channel 2q+1
    // head mean: partner channels 2q+32, 2q+33 live as (v0,v1) of lane (q&15)+16
    float p0 = __shfl(v0, (t & 15) + 16, 64);
    float p1 = __shfl(v1, (t & 15) + 16, 64);
    if (t < 16) {
        const int c0 = 2 * t;
        float m0 = 0.5f * (v0 + p0) + b2[c0];
        float m1 = 0.5f * (v1 + p1) + b2[c0 + 1];
        m0 = (m0 - mu[c0]) * rsqrtf(var[c0] + BN_EPS) * g[c0] + be[c0];
        m1 = (m1 - mu[c0 + 1]) * rsqrtf(var[c0 + 1] + BN_EPS) * g[c0 + 1] + be[c0 + 1];
        *(float2*)(node_out + (size_t)node * 32 + c0) = make_float2(m0, m1);
    }
}

// ============ block-per-graph: mean over nodes + log_softmax (32 classes) ============
__global__ __launch_bounds__(256) void pool_logsoftmax(
    const float* __restrict__ node_out, const int* __restrict__ gstart,
    float* __restrict__ out) {
    const int gidx = blockIdx.x;
    const int tid = threadIdx.x;
    const int c = tid & 31, r = tid >> 5;  // 8 node-rows
    const int n0 = gstart[gidx], n1 = gstart[gidx + 1];
    float s = 0.f;
    for (int n = n0 + r; n < n1; n += 8) s += node_out[(size_t)n * 32 + c];
    __shared__ float red[8][32];
    red[r][c] = s;
    __syncthreads();
    if (r == 0) {
        float tot = red[0][c];
#pragma unroll
        for (int k = 1; k < 8; ++k) tot += red[k][c];
        float v = tot / fmaxf((float)(n1 - n0), 1.f);
        float m = v;
#pragma unroll
        for (int off = 16; off >= 1; off >>= 1) m = fmaxf(m, __shfl_xor(m, off, 64));
        float ex = __expf(v - m);
        float ssum = ex;
#pragma unroll
        for (int off = 16; off >= 1; off >>= 1) ssum += __shfl_xor(ssum, off, 64);
        out[gidx * 32 + c] = v - m - logf(ssum);
    }
}

extern "C" void kernel_launch(void* const* d_in, const int* in_sizes, int n_in,
                              void* d_out, int out_size, void* d_ws, size_t ws_size,
                              hipStream_t stream) {
    const float* x   = (const float*)d_in[0];
    const int* ei    = (const int*)d_in[1];
    const int* batch = (const int*)d_in[2];
    const float* W1  = (const float*)d_in[3];
    const float* as1 = (const float*)d_in[4];
    const float* ad1 = (const float*)d_in[5];
    const float* b1  = (const float*)d_in[6];
    const float* g1  = (const float*)d_in[7];
    const float* be1 = (const float*)d_in[8];
    const float* mu1 = (const float*)d_in[9];
    const float* vr1 = (const float*)d_in[10];
    const float* W2  = (const float*)d_in[11];
    const float* as2 = (const float*)d_in[12];
    const float* ad2 = (const float*)d_in[13];
    const float* b2  = (const float*)d_in[14];
    const float* g2  = (const float*)d_in[15];
    const float* be2 = (const float*)d_in[16];
    const float* mu2 = (const float*)d_in[17];
    const float* vr2 = (const float*)d_in[18];
    float* out = (float*)d_out;

    const int N = in_sizes[0] / 128;
    const int E = in_sizes[1] / 2;
    const int Etot = E + N;
    const int G = out_size / 32;
    const int NB = (N + 1023) / 1024;

    // ---- workspace layout ----
    float* p = (float*)d_ws;
    size_t o = 0;
    ushort16* h1 = (ushort16*)(p + o); o += (size_t)N * 64;   // N*128 bf16
    ushort16* h2 = (ushort16*)(p + o); o += (size_t)N * 32;   // N*64 bf16
    float* agg1  = p + o; o += (size_t)N * 128;
    float* nodeo = p + o; o += (size_t)N * 32;
    float* asrc1 = p + o; o += (size_t)N * 2;
    float* adst1 = p + o; o += (size_t)N * 2;
    float* asrc2 = p + o; o += (size_t)N * 2;
    float* adst2 = p + o; o += (size_t)N * 2;
    int* csr_src = (int*)(p + o); o += (size_t)Etot;
    int* base    = (int*)(p + o); o += (size_t)N;
    int* bsum    = (int*)(p + o); o += 256;
    int* gstart  = (int*)(p + o); o += (size_t)G + 1;
    // zero-initialized region (one memset):
    float* zbase = p + o;
    int* deg     = (int*)(p + o); o += (size_t)N;
    int* cursor  = (int*)(p + o); o += (size_t)N;
    const size_t zbytes = (size_t)(p + o - zbase) * sizeof(float);
    hipMemsetAsync(zbase, 0, zbytes, stream);

    // ---- CSR build (by destination) + graph bounds ----
    deg_count<<<(Etot + 255) / 256, 256, 0, stream>>>(ei, E, Etot, deg);
    scan_block<<<NB, 1024, 0, stream>>>(deg, base, bsum, N);
    scan_bsum<<<1, 64, 0, stream>>>(bsum, NB);
    scan_add<<<NB, 1024, 0, stream>>>(base, bsum, N);
    csr_scatter<<<(Etot + 255) / 256, 256, 0, stream>>>(ei, E, Etot, base, cursor, csr_src);
    graph_bounds<<<(G + 256) / 256, 256, 0, stream>>>(batch, N, G, gstart);

    // ---- layer 1 ----
    gemm_att_tiled<128, 128, 64><<<(N + 127) / 128, 256, 0, stream>>>(
        x, W1, as1, ad1, h1, asrc1, adst1, N);
    gat_gather1<<<(N + 3) / 4, 256, 0, stream>>>(base, csr_src, Etot, N, h1, asrc1, adst1,
                                                 b1, g1, be1, mu1, vr1, agg1);
    // ---- layer 2 ----
    gemm_att_tiled<128, 64, 32><<<(N + 127) / 128, 256, 0, stream>>>(
        agg1, W2, as2, ad2, h2, asrc2, adst2, N);
    gat_gather2<<<(N + 3) / 4, 256, 0, stream>>>(base, csr_src, Etot, N, h2, asrc2, adst2,
                                                 b2, g2, be2, mu2, vr2, nodeo);

    // ---- epilogue ----
    pool_logsoftmax<<<G, 256, 0, stream>>>(nodeo, gstart, out);
}

// Round 6
// 324.321 us; speedup vs baseline: 1.4862x; 1.2103x over previous
//
#include <hip/hip_runtime.h>
#include <hip/hip_bf16.h>

#define NEG_SLOPE 0.2f
#define BN_EPS 1e-5f

typedef unsigned int uint32;
typedef unsigned short ushort16;
typedef __attribute__((ext_vector_type(8))) short bf16x8;
typedef __attribute__((ext_vector_type(4))) float f32x4;

__device__ __forceinline__ ushort16 f2bf(float f) {
    uint32 u = __float_as_uint(f);
    u = (u + 0x7fff + ((u >> 16) & 1)) >> 16;  // round-to-nearest-even
    return (ushort16)u;
}
__device__ __forceinline__ float bfu_lo(uint32 u) { return __uint_as_float(u << 16); }
__device__ __forceinline__ float bfu_hi(uint32 u) { return __uint_as_float(u & 0xffff0000u); }

// ============================ CSR construction ============================
__global__ void deg_count(const int* __restrict__ ei, int E, int Etot, int* __restrict__ deg) {
    int i = blockIdx.x * blockDim.x + threadIdx.x;
    if (i >= Etot) return;
    int d = (i < E) ? ei[E + i] : i - E;
    atomicAdd(&deg[d], 1);
}

__global__ void scan_block(const int* __restrict__ deg, int* __restrict__ base,
                           int* __restrict__ bsum, int n) {
    __shared__ int s[1024];
    int gid = blockIdx.x * 1024 + threadIdx.x;
    int v = (gid < n) ? deg[gid] : 0;
    s[threadIdx.x] = v;
    __syncthreads();
    for (int off = 1; off < 1024; off <<= 1) {
        int t = (threadIdx.x >= off) ? s[threadIdx.x - off] : 0;
        __syncthreads();
        s[threadIdx.x] += t;
        __syncthreads();
    }
    if (gid < n) base[gid] = s[threadIdx.x] - v;  // exclusive
    if (threadIdx.x == 1023) bsum[blockIdx.x] = s[1023];
}

__global__ void scan_bsum(int* __restrict__ bsum, int nb) {
    if (threadIdx.x == 0 && blockIdx.x == 0) {
        int acc = 0;
        for (int i = 0; i < nb; ++i) { int t = bsum[i]; bsum[i] = acc; acc += t; }
    }
}

__global__ void scan_add(int* __restrict__ base, const int* __restrict__ bsum, int n) {
    int gid = blockIdx.x * 1024 + threadIdx.x;
    if (gid < n) base[gid] += bsum[blockIdx.x];
}

__global__ void csr_scatter(const int* __restrict__ ei, int E, int Etot,
                            const int* __restrict__ base, int* __restrict__ cursor,
                            int* __restrict__ csr_src) {
    int i = blockIdx.x * blockDim.x + threadIdx.x;
    if (i >= Etot) return;
    int s_, d_;
    if (i < E) { s_ = ei[i]; d_ = ei[E + i]; }
    else       { s_ = d_ = i - E; }
    int pos = base[d_] + atomicAdd(&cursor[d_], 1);
    csr_src[pos] = s_;
}

// gstart[g] = first node with batch[node] >= g (batch sorted); gstart[G] = N.
__global__ void graph_bounds(const int* __restrict__ batch, int N, int G,
                             int* __restrict__ gstart) {
    int g = blockIdx.x * blockDim.x + threadIdx.x;
    if (g > G) return;
    if (g == G) { gstart[G] = N; return; }
    int lo = 0, hi = N;
    while (lo < hi) { int mid = (lo + hi) >> 1; if (batch[mid] < g) lo = mid + 1; else hi = mid; }
    gstart[g] = lo;
}

// ================== pack W (+ attention columns) transposed, bf16 ==================
// wt[col][k] (row-major, 128 k's per row). Columns: [0,OC)=W; OC..OC+1 = W·a_s (head 0,1);
// OC+2..OC+3 = W·a_d; rest zero-pad to NT*16.
template <int OC, int C>
__global__ void pack_w(const float* __restrict__ W, const float* __restrict__ a_s,
                       const float* __restrict__ a_d, ushort16* __restrict__ wt) {
    const int col = blockIdx.x;
    const int k = threadIdx.x;  // 0..127
    float v = 0.f;
    if (col < OC) {
        v = W[k * OC + col];
    } else if (col < OC + 2) {
        int hh = col - OC;
        float s = 0.f;
        for (int c = 0; c < C; ++c) s += W[k * OC + hh * C + c] * a_s[hh * C + c];
        v = s;
    } else if (col < OC + 4) {
        int hh = col - OC - 2;
        float s = 0.f;
        for (int c = 0; c < C; ++c) s += W[k * OC + hh * C + c] * a_d[hh * C + c];
        v = s;
    }
    wt[(size_t)col * 128 + k] = f2bf(v);
}

// ==================== MFMA GEMM: h = x @ Wext (K=128) ====================
// One wave per 16-node tile; A-frags in registers (from fp32 or bf16 source),
// B-frags from packed wt. Last channel tile writes att = (as_h0,as_h1,ad_h0,ad_h1) fp32.
template <int OC, int NT, bool AF32>
__global__ __launch_bounds__(256) void gemm_mfma(
    const void* __restrict__ xin, const ushort16* __restrict__ wt,
    ushort16* __restrict__ h, float4* __restrict__ att, int N) {
    const int wave = threadIdx.x >> 6, lane = threadIdx.x & 63;
    const int tile = blockIdx.x * 4 + wave;
    if (tile * 16 >= N) return;
    const int m = lane & 15, quad = lane >> 4;
    const int node = tile * 16 + m;

    bf16x8 a[4];
    if (AF32) {
        const float* xr = (const float*)xin + (size_t)node * 128 + quad * 8;
#pragma unroll
        for (int c = 0; c < 4; ++c) {
            float4 u = *(const float4*)(xr + c * 32);
            float4 v = *(const float4*)(xr + c * 32 + 4);
            bf16x8 t;
            t[0] = (short)f2bf(u.x); t[1] = (short)f2bf(u.y);
            t[2] = (short)f2bf(u.z); t[3] = (short)f2bf(u.w);
            t[4] = (short)f2bf(v.x); t[5] = (short)f2bf(v.y);
            t[6] = (short)f2bf(v.z); t[7] = (short)f2bf(v.w);
            a[c] = t;
        }
    } else {
        const ushort16* xr = (const ushort16*)xin + (size_t)node * 128 + quad * 8;
#pragma unroll
        for (int c = 0; c < 4; ++c) a[c] = *(const bf16x8*)(xr + c * 32);
    }

    for (int t = 0; t < NT; ++t) {
        const ushort16* wr = wt + ((size_t)(t * 16 + m)) * 128 + quad * 8;
        bf16x8 b[4];
#pragma unroll
        for (int c = 0; c < 4; ++c) b[c] = *(const bf16x8*)(wr + c * 32);
        f32x4 acc = {0.f, 0.f, 0.f, 0.f};
#pragma unroll
        for (int c = 0; c < 4; ++c)
            acc = __builtin_amdgcn_mfma_f32_16x16x32_bf16(a[c], b[c], acc, 0, 0, 0);
        if (t * 16 < OC) {
#pragma unroll
            for (int r = 0; r < 4; ++r) {
                int nrow = tile * 16 + quad * 4 + r;
                h[(size_t)nrow * OC + t * 16 + m] = f2bf(acc[r]);
            }
        } else if (m < 4) {
#pragma unroll
            for (int r = 0; r < 4; ++r) {
                int nrow = tile * 16 + quad * 4 + r;
                ((float*)(att + nrow))[m] = acc[r];
            }
        }
    }
}

// ================= layer-1 gather: softmax-agg + bias + BN + ReLU -> bf16 =================
// 4 nodes / 256-thread block, one wave per node. Half-wave per edge-slot parity;
// lane owns 4 channels (uint2 of bf16).
__global__ __launch_bounds__(256) void gat_gather1(
    const int* __restrict__ base, const int* __restrict__ csr_src, int Etot, int N,
    const ushort16* __restrict__ h, const float4* __restrict__ att,
    const float* __restrict__ b, const float* __restrict__ g, const float* __restrict__ be,
    const float* __restrict__ mu, const float* __restrict__ var,
    ushort16* __restrict__ outb) {
    const int node = __builtin_amdgcn_readfirstlane(blockIdx.x * 4 + (threadIdx.x >> 6));
    if (node >= N) return;
    const int t = threadIdx.x & 63;
    const int half = t >> 5;
    const int q = t & 31;      // channels 4q..4q+3
    const int hh = q >> 4;     // head
    const int beg = base[node];
    const int end = (node + 1 < N) ? base[node + 1] : Etot;
    const int deg = end - beg;
    const int nk = (deg - half + 1) >> 1;
    const int nkmax = (deg + 1) >> 1;
    const float4 adn = att[node];
    const float advh = hh ? adn.w : adn.z;

    float a0 = 0.f, a1 = 0.f, a2 = 0.f, a3 = 0.f, ssum = 0.f;
    constexpr int U = 4;
    for (int k = 0; k < nkmax; k += U) {
        int sidx[U];
        float msk[U];
#pragma unroll
        for (int j = 0; j < U; ++j) {
            int kk = k + j;
            bool ok = kk < nk;
            sidx[j] = csr_src[beg + (ok ? 2 * kk + half : 0)];
            msk[j] = ok ? 1.f : 0.f;
        }
        float4 av[U];
        uint2 hv[U];
#pragma unroll
        for (int j = 0; j < U; ++j) {
            av[j] = att[sidx[j]];
            hv[j] = *(const uint2*)(h + (size_t)sidx[j] * 128 + 4 * q);
        }
#pragma unroll
        for (int j = 0; j < U; ++j) {
            float ev = (hh ? av[j].y : av[j].x) + advh;
            ev = ev > 0.f ? ev : NEG_SLOPE * ev;
            float ex = __expf(ev) * msk[j];
            a0 += ex * bfu_lo(hv[j].x);
            a1 += ex * bfu_hi(hv[j].x);
            a2 += ex * bfu_lo(hv[j].y);
            a3 += ex * bfu_hi(hv[j].y);
            ssum += ex;
        }
    }
    a0 += __shfl_xor(a0, 32, 64);
    a1 += __shfl_xor(a1, 32, 64);
    a2 += __shfl_xor(a2, 32, 64);
    a3 += __shfl_xor(a3, 32, 64);
    ssum += __shfl_xor(ssum, 32, 64);
    if (half == 0) {
        const float inv = 1.f / (ssum + 1e-16f);
        const int c0 = 4 * q;
        float4 bb = *(const float4*)(b + c0);
        float4 gg = *(const float4*)(g + c0);
        float4 ee = *(const float4*)(be + c0);
        float4 mm = *(const float4*)(mu + c0);
        float4 vv = *(const float4*)(var + c0);
        float v0 = a0 * inv + bb.x, v1 = a1 * inv + bb.y;
        float v2 = a2 * inv + bb.z, v3 = a3 * inv + bb.w;
        v0 = fmaxf((v0 - mm.x) * rsqrtf(vv.x + BN_EPS) * gg.x + ee.x, 0.f);
        v1 = fmaxf((v1 - mm.y) * rsqrtf(vv.y + BN_EPS) * gg.y + ee.y, 0.f);
        v2 = fmaxf((v2 - mm.z) * rsqrtf(vv.z + BN_EPS) * gg.z + ee.z, 0.f);
        v3 = fmaxf((v3 - mm.w) * rsqrtf(vv.w + BN_EPS) * gg.w + ee.w, 0.f);
        uint2 r;
        r.x = (uint32)f2bf(v0) | ((uint32)f2bf(v1) << 16);
        r.y = (uint32)f2bf(v2) | ((uint32)f2bf(v3) << 16);
        *(uint2*)(outb + (size_t)node * 128 + c0) = r;
    }
}

// ====== layer-2 gather: softmax-agg + head-mean + bias + BN -> node_out (no atomics) ======
__global__ __launch_bounds__(256) void gat_gather2(
    const int* __restrict__ base, const int* __restrict__ csr_src, int Etot, int N,
    const ushort16* __restrict__ h2, const float4* __restrict__ att,
    const float* __restrict__ b2, const float* __restrict__ g, const float* __restrict__ be,
    const float* __restrict__ mu, const float* __restrict__ var,
    float* __restrict__ node_out) {
    const int node = __builtin_amdgcn_readfirstlane(blockIdx.x * 4 + (threadIdx.x >> 6));
    if (node >= N) return;
    const int t = threadIdx.x & 63;
    const int half = t >> 5;
    const int q = t & 31;      // channels 2q, 2q+1
    const int hh = q >> 4;     // head
    const int beg = base[node];
    const int end = (node + 1 < N) ? base[node + 1] : Etot;
    const int deg = end - beg;
    const int nk = (deg - half + 1) >> 1;
    const int nkmax = (deg + 1) >> 1;
    const float4 adn = att[node];
    const float advh = hh ? adn.w : adn.z;

    float accx = 0.f, accy = 0.f, ssum = 0.f;
    constexpr int U = 4;
    for (int k = 0; k < nkmax; k += U) {
        int sidx[U];
        float msk[U];
#pragma unroll
        for (int j = 0; j < U; ++j) {
            int kk = k + j;
            bool ok = kk < nk;
            sidx[j] = csr_src[beg + (ok ? 2 * kk + half : 0)];
            msk[j] = ok ? 1.f : 0.f;
        }
        float4 av[U];
        uint32 hv[U];
#pragma unroll
        for (int j = 0; j < U; ++j) {
            av[j] = att[sidx[j]];
            hv[j] = *(const uint32*)(h2 + (size_t)sidx[j] * 64 + 2 * q);
        }
#pragma unroll
        for (int j = 0; j < U; ++j) {
            float ev = (hh ? av[j].y : av[j].x) + advh;
            ev = ev > 0.f ? ev : NEG_SLOPE * ev;
            float ex = __expf(ev) * msk[j];
            accx += ex * bfu_lo(hv[j]);
            accy += ex * bfu_hi(hv[j]);
            ssum += ex;
        }
    }
    accx += __shfl_xor(accx, 32, 64);
    accy += __shfl_xor(accy, 32, 64);
    ssum += __shfl_xor(ssum, 32, 64);
    const float inv = 1.f / (ssum + 1e-16f);
    float v0 = accx * inv;
    float v1 = accy * inv;
    float p0 = __shfl(v0, (t & 15) + 16, 64);
    float p1 = __shfl(v1, (t & 15) + 16, 64);
    if (t < 16) {
        const int c0 = 2 * t;
        float m0 = 0.5f * (v0 + p0) + b2[c0];
        float m1 = 0.5f * (v1 + p1) + b2[c0 + 1];
        m0 = (m0 - mu[c0]) * rsqrtf(var[c0] + BN_EPS) * g[c0] + be[c0];
        m1 = (m1 - mu[c0 + 1]) * rsqrtf(var[c0 + 1] + BN_EPS) * g[c0 + 1] + be[c0 + 1];
        *(float2*)(node_out + (size_t)node * 32 + c0) = make_float2(m0, m1);
    }
}

// ============ block-per-graph: mean over nodes + log_softmax (32 classes) ============
__global__ __launch_bounds__(256) void pool_logsoftmax(
    const float* __restrict__ node_out, const int* __restrict__ gstart,
    float* __restrict__ out) {
    const int gidx = blockIdx.x;
    const int tid = threadIdx.x;
    const int c = tid & 31, r = tid >> 5;
    const int n0 = gstart[gidx], n1 = gstart[gidx + 1];
    float s = 0.f;
    for (int n = n0 + r; n < n1; n += 8) s += node_out[(size_t)n * 32 + c];
    __shared__ float red[8][32];
    red[r][c] = s;
    __syncthreads();
    if (r == 0) {
        float tot = red[0][c];
#pragma unroll
        for (int k = 1; k < 8; ++k) tot += red[k][c];
        float v = tot / fmaxf((float)(n1 - n0), 1.f);
        float m = v;
#pragma unroll
        for (int off = 16; off >= 1; off >>= 1) m = fmaxf(m, __shfl_xor(m, off, 64));
        float ex = __expf(v - m);
        float ssum = ex;
#pragma unroll
        for (int off = 16; off >= 1; off >>= 1) ssum += __shfl_xor(ssum, off, 64);
        out[gidx * 32 + c] = v - m - logf(ssum);
    }
}

extern "C" void kernel_launch(void* const* d_in, const int* in_sizes, int n_in,
                              void* d_out, int out_size, void* d_ws, size_t ws_size,
                              hipStream_t stream) {
    const float* x   = (const float*)d_in[0];
    const int* ei    = (const int*)d_in[1];
    const int* batch = (const int*)d_in[2];
    const float* W1  = (const float*)d_in[3];
    const float* as1 = (const float*)d_in[4];
    const float* ad1 = (const float*)d_in[5];
    const float* b1  = (const float*)d_in[6];
    const float* g1  = (const float*)d_in[7];
    const float* be1 = (const float*)d_in[8];
    const float* mu1 = (const float*)d_in[9];
    const float* vr1 = (const float*)d_in[10];
    const float* W2  = (const float*)d_in[11];
    const float* as2 = (const float*)d_in[12];
    const float* ad2 = (const float*)d_in[13];
    const float* b2  = (const float*)d_in[14];
    const float* g2  = (const float*)d_in[15];
    const float* be2 = (const float*)d_in[16];
    const float* mu2 = (const float*)d_in[17];
    const float* vr2 = (const float*)d_in[18];
    float* out = (float*)d_out;

    const int N = in_sizes[0] / 128;
    const int E = in_sizes[1] / 2;
    const int Etot = E + N;
    const int G = out_size / 32;
    const int NB = (N + 1023) / 1024;
    const int ntile = (N + 15) / 16;
    const int gemm_grid = (ntile + 3) / 4;

    // ---- workspace layout (units: floats; keep every region 16B-aligned) ----
    float* p = (float*)d_ws;
    size_t o = 0;
    auto al = [&]() { o = (o + 3) & ~(size_t)3; };
    ushort16* h1b   = (ushort16*)(p + o); o += (size_t)N * 64;  al();  // N*128 bf16
    ushort16* agg1b = (ushort16*)(p + o); o += (size_t)N * 64;  al();  // N*128 bf16
    ushort16* h2b   = (ushort16*)(p + o); o += (size_t)N * 32;  al();  // N*64 bf16
    float4* att1 = (float4*)(p + o); o += (size_t)N * 4;  al();
    float4* att2 = (float4*)(p + o); o += (size_t)N * 4;  al();
    float* nodeo = p + o; o += (size_t)N * 32; al();
    ushort16* wt1 = (ushort16*)(p + o); o += (size_t)144 * 64; al();   // 144x128 bf16
    ushort16* wt2 = (ushort16*)(p + o); o += (size_t)80 * 64;  al();   // 80x128 bf16
    int* csr_src = (int*)(p + o); o += (size_t)Etot; al();
    int* base    = (int*)(p + o); o += (size_t)N;    al();
    int* bsum    = (int*)(p + o); o += 256;
    int* gstart  = (int*)(p + o); o += (size_t)G + 4; al();
    // zero-initialized region (one memset):
    float* zbase = p + o;
    int* deg     = (int*)(p + o); o += (size_t)N; al();
    int* cursor  = (int*)(p + o); o += (size_t)N; al();
    const size_t zbytes = (size_t)(p + o - zbase) * sizeof(float);
    hipMemsetAsync(zbase, 0, zbytes, stream);

    // ---- CSR build (by destination) + graph bounds + weight pack ----
    deg_count<<<(Etot + 255) / 256, 256, 0, stream>>>(ei, E, Etot, deg);
    scan_block<<<NB, 1024, 0, stream>>>(deg, base, bsum, N);
    scan_bsum<<<1, 64, 0, stream>>>(bsum, NB);
    scan_add<<<NB, 1024, 0, stream>>>(base, bsum, N);
    csr_scatter<<<(Etot + 255) / 256, 256, 0, stream>>>(ei, E, Etot, base, cursor, csr_src);
    graph_bounds<<<(G + 256) / 256, 256, 0, stream>>>(batch, N, G, gstart);
    pack_w<128, 64><<<144, 128, 0, stream>>>(W1, as1, ad1, wt1);
    pack_w<64, 32><<<80, 128, 0, stream>>>(W2, as2, ad2, wt2);

    // ---- layer 1 ----
    gemm_mfma<128, 9, true><<<gemm_grid, 256, 0, stream>>>(x, wt1, h1b, att1, N);
    gat_gather1<<<(N + 3) / 4, 256, 0, stream>>>(base, csr_src, Etot, N, h1b, att1,
                                                 b1, g1, be1, mu1, vr1, agg1b);
    // ---- layer 2 ----
    gemm_mfma<64, 5, false><<<gemm_grid, 256, 0, stream>>>(agg1b, wt2, h2b, att2, N);
    gat_gather2<<<(N + 3) / 4, 256, 0, stream>>>(base, csr_src, Etot, N, h2b, att2,
                                                 b2, g2, be2, mu2, vr2, nodeo);

    // ---- epilogue ----
    pool_logsoftmax<<<G, 256, 0, stream>>>(nodeo, gstart, out);
}